// Round 10
// baseline (161.643 us; speedup 1.0000x reference)
//
#include <hip/hip_runtime.h>

// VectorQuantizer forward: inputs [64,2048,64] f32, codebook [1024,64] f32.
// Outputs (f32, concat): quantized_ste [8388608], loss [1], indices-as-float [131072].
//
// Round 18: R17's fragment-contiguous swizzle confirmed the TA/address-path
// theory (163->88us). Remaining: ~21% idle (no cross-ct prefetch), ~70us of
// per-iteration prep+overhead (vq_prep ran 4 blocks on 256 CUs), and a VALU
// pipe at 55%. Three orthogonal fixes:
//  (1) vq_prep parallelized 16x: 4 threads/code, exact quarter chains
//      combined via shfl_xor in (p0+p1)+(p2+p3) order.
//  (2) codebook pre-scaled by -2^19 (exact pow2 on both bf16 splits) and
//      cs18b folded into the MFMA C-init -> acc_final = csb - 2^19*dot = m18
//      directly; per-pair key path = cvt + lshl_or + 5-op network (fma gone).
//      Extra f32 rounding (accumulating at 2^18 scale, ~3-4 quanta worst)
//      absorbed by widened margins: hot 26->48, Mq const 5->24. Recheck path
//      is exact, so only top-3 containment matters (gap stats give >>10x slack).
//  (3) 1-deep register prefetch of next B-tile + csb, unconditional stride
//      into a padded 65th tile (garbage loads never consumed).
//
// Numerics: approx path margins widened as above; exact path unchanged
// (sequential fmaf k=0..63, fl(fl(asq-2acc)+cs), u64 first-index-wins).
// C/D layout: col=lane&15, row=(lane>>4)*4+reg (HW-verified). Loss/STE
// epilogue in identical 64-row units (2048 identical partials).

#define NROWS  131072
#define DIM    64
#define KCB    1024
#define QSIZE  (NROWS * DIM)  // 8388608

typedef unsigned long long u64;
typedef unsigned int u32;
typedef unsigned short ushortx;
typedef __attribute__((ext_vector_type(8))) short short8v;
typedef __attribute__((ext_vector_type(4))) float f32x4;

__device__ __forceinline__ u32 umin32(u32 a, u32 b) { return a < b ? a : b; }
__device__ __forceinline__ u32 umax32(u32 a, u32 b) { return a > b ? a : b; }

// RNE f32 -> bf16 (deterministic, internal-only precision split)
__device__ __forceinline__ ushortx f2bf(float f) {
    u32 u = __float_as_uint(f);
    u32 r = u + 0x7FFFu + ((u >> 16) & 1u);
    return (ushortx)(r >> 16);
}
__device__ __forceinline__ float bf2f(ushortx h) {
    return __uint_as_float(((u32)h) << 16);
}

// ---- prep (parallel, 16 blocks x 256): csq exact quarter chains (4
// ---- threads/code, shfl-combined), cs18b, and the swizzled codebook
// ---- PRE-SCALED by -2^19 (exact on both splits).
// Layout (ushort units): tile ct stride 2048; sections of 512:
//   [ct*2048 + h*512        + L*8] = hi of -2^19*cb[16ct+(L&15)][h*32+(L>>4)*8..+8]
//   [ct*2048 + 1024 + h*512 + L*8] = lo of same
__global__ __launch_bounds__(256) void vq_prep(const float* __restrict__ cb,
                                               float* __restrict__ csq,
                                               float* __restrict__ cs18b,
                                               ushortx* __restrict__ cbsw,
                                               float* __restrict__ loss_slot) {
    const int gid = blockIdx.x * 256 + threadIdx.x;   // 0..4095
    const int k  = gid >> 2;        // code 0..1023
    const int qt = gid & 3;         // dim quarter 16qt..16qt+15
    const float* c = cb + k * DIM;

    // exact 16-dim quarter chain
    float aq = 0.f;
    #pragma unroll
    for (int d = 0; d < 16; ++d) {
        const float v = c[16 * qt + d];
        aq = fmaf(v, v, aq);
    }
    // combine within 4-lane group: (p0+p1)+(p2+p3) exact order
    const float s1 = aq + __shfl_xor(aq, 1, 64);
    const float s2 = s1 + __shfl_xor(s1, 2, 64);
    if (qt == 0) {
        csq[k]   = s2;
        cs18b[k] = s2 * 262144.0f + 131072.0f;   // cs*2^18 + 2^17 bias
    }

    // swizzled pre-scaled writes: quarter qt covers 8-dim chunks 2qt, 2qt+1
    const int ct = k >> 4;
    const int j  = k & 15;
    #pragma unroll
    for (int cc = 0; cc < 2; ++cc) {
        const int c8 = 2 * qt + cc;     // global 8-dim chunk 0..7
        const int h  = c8 >> 2;         // dim half
        const int qq = c8 & 3;          // k-chunk within half
        const int L  = qq * 16 + j;     // destination lane
        union { ushortx u[8]; short8v v; } uh, ul;
        #pragma unroll
        for (int e = 0; e < 8; ++e) {
            const float g = c[c8 * 8 + e] * -524288.0f;   // exact scale -2^19
            const ushortx hh = f2bf(g);
            uh.u[e] = hh;
            ul.u[e] = f2bf(g - bf2f(hh));
        }
        *reinterpret_cast<short8v*>(cbsw + ct * 2048 + h * 512 + L * 8) = uh.v;
        *reinterpret_cast<short8v*>(cbsw + ct * 2048 + 1024 + h * 512 + L * 8) = ul.v;
    }
    if (gid == 0) *loss_slot = 0.f;
}

// ---- main: 256 threads = 4 waves; block = 128 rows (wave owns 32 rows =
// ---- 2 MFMA rowtiles -> 2 independent acc chains; sweeps all 1024 codes) ----
__global__ __launch_bounds__(256, 4) void vq_main(const float* __restrict__ x,
                                                  const float* __restrict__ cb,
                                                  const float* __restrict__ csq,
                                                  const float* __restrict__ cs18b,
                                                  const ushortx* __restrict__ cbsw,
                                                  float* __restrict__ out_q,
                                                  float* __restrict__ out_loss,
                                                  float* __restrict__ out_idx) {
    __shared__ u32   sTop[4][32][3];
    __shared__ int   sFinal[128];
    __shared__ float sLoss[4];

    const int tid  = threadIdx.x;
    const int lane = tid & 63;
    const int wid  = tid >> 6;            // 0..3
    const size_t rowbase = (size_t)blockIdx.x * 128;
    const int wrow0 = wid * 32;           // block-local first row of this wave
    const int lcol  = lane & 15;          // A-row-in-tile / B-col / D-col
    const int lkq   = lane >> 4;          // k-chunk 0..3

    // ---- A fragments: 2 rowtiles x 2 k-halves, hi/lo bf16 splits ----
    short8v Ah[2][2], Al[2][2];
    #pragma unroll
    for (int t = 0; t < 2; ++t)
        #pragma unroll
        for (int h = 0; h < 2; ++h) {
            const float* xp = x + (rowbase + (size_t)(wrow0 + t * 16 + lcol)) * DIM
                              + h * 32 + lkq * 8;
            const float4 u0 = *reinterpret_cast<const float4*>(xp);
            const float4 u1 = *reinterpret_cast<const float4*>(xp + 4);
            const float xv[8] = {u0.x, u0.y, u0.z, u0.w, u1.x, u1.y, u1.z, u1.w};
            union { ushortx u[8]; short8v v; } uh, ul;
            #pragma unroll
            for (int j = 0; j < 8; ++j) {
                const ushortx hh = f2bf(xv[j]);
                uh.u[j] = hh;
                ul.u[j] = f2bf(xv[j] - bf2f(hh));
            }
            Ah[t][h] = uh.v;
            Al[t][h] = ul.v;
        }

    // ---- code sweep: top-3 u32 keys per row-slot (8 slots/lane) ----
    u32 k1[8], k2[8], k3[8];
    #pragma unroll
    for (int s = 0; s < 8; ++s) { k1[s] = ~0u; k2[s] = ~0u; k3[s] = ~0u; }

    u32 nlane = (u32)lcol;
    const ushortx* bp = cbsw + (size_t)lane * 8;   // ideal coalesced: lane*16B

    // 1-deep prefetch (tile 64 is an uninitialized pad; its values unused)
    short8v pBh0 = *reinterpret_cast<const short8v*>(bp);
    short8v pBh1 = *reinterpret_cast<const short8v*>(bp + 512);
    short8v pBl0 = *reinterpret_cast<const short8v*>(bp + 1024);
    short8v pBl1 = *reinterpret_cast<const short8v*>(bp + 1536);
    float   pcs  = cs18b[nlane];

    #pragma unroll 1
    for (int ct = 0; ct < 64; ++ct) {     // 16 codes per tile
        const short8v Bh0 = pBh0, Bh1 = pBh1, Bl0 = pBl0, Bl1 = pBl1;
        const float csb = pcs;
        bp += 2048;
        pBh0 = *reinterpret_cast<const short8v*>(bp);
        pBh1 = *reinterpret_cast<const short8v*>(bp + 512);
        pBl0 = *reinterpret_cast<const short8v*>(bp + 1024);
        pBl1 = *reinterpret_cast<const short8v*>(bp + 1536);
        pcs  = cs18b[nlane + 16];         // last iter reads past-end scratch, unused

        #pragma unroll
        for (int t = 0; t < 2; ++t) {     // 2 independent acc chains (ILP)
            f32x4 acc = (f32x4){csb, csb, csb, csb};   // C-init = cs*2^18 + bias
            acc = __builtin_amdgcn_mfma_f32_16x16x32_bf16(Ah[t][0], Bh0, acc, 0, 0, 0);
            acc = __builtin_amdgcn_mfma_f32_16x16x32_bf16(Al[t][0], Bh0, acc, 0, 0, 0);
            acc = __builtin_amdgcn_mfma_f32_16x16x32_bf16(Ah[t][0], Bl0, acc, 0, 0, 0);
            acc = __builtin_amdgcn_mfma_f32_16x16x32_bf16(Ah[t][1], Bh1, acc, 0, 0, 0);
            acc = __builtin_amdgcn_mfma_f32_16x16x32_bf16(Al[t][1], Bh1, acc, 0, 0, 0);
            acc = __builtin_amdgcn_mfma_f32_16x16x32_bf16(Ah[t][1], Bl1, acc, 0, 0, 0);
            // acc[r] = csb - 2^19*dot = m18 directly (B pre-scaled by -2^19)
            #pragma unroll
            for (int r = 0; r < 4; ++r) {
                const u32 key = ((u32)acc[r] << 10) | nlane;   // trunc-cvt, monotone
                const int s = t * 4 + r;
                const u32 nk1 = umin32(key, k1[s]);
                const u32 mx  = umax32(key, k1[s]);
                const u32 nk2 = umin32(k2[s], mx);
                const u32 mx2 = umax32(k2[s], mx);
                k3[s] = umin32(k3[s], mx2);
                k1[s] = nk1; k2[s] = nk2;
            }
        }
        nlane += 16;
    }

    // ---- merge the 16 col-classes per row (butterfly over lanes 16g..16g+15) ----
    #pragma unroll
    for (int s = 0; s < 8; ++s) {
        u32 a1 = k1[s], a2 = k2[s], a3 = k3[s];
        #pragma unroll
        for (int mask = 1; mask <= 8; mask <<= 1) {
            const u32 b1 = __shfl_xor(a1, mask, 64);
            const u32 b2 = __shfl_xor(a2, mask, 64);
            const u32 b3 = __shfl_xor(a3, mask, 64);
            const u32 c1 = umin32(a1, b1), d1 = umax32(a1, b1);
            const u32 c2 = umin32(a2, b2);
            const u32 o3 = umin32(umax32(d1, c2), umin32(a3, b3));
            a1 = c1; a2 = umin32(d1, c2); a3 = o3;
        }
        k1[s] = a1; k2[s] = a2; k3[s] = a3;
    }
    if (lcol < 8) {   // lane 16g+j writes slot j -> row (j>>2)*16 + g*4 + (j&3)
        const int j = lcol, g = lkq;
        const int row = (j >> 2) * 16 + g * 4 + (j & 3);
        sTop[wid][row][0] = k1[j]; sTop[wid][row][1] = k2[j]; sTop[wid][row][2] = k3[j];
    }
    __syncthreads();

    // ---- per-row final: non-hot -> min1; hot -> exact d2 (R12 chain) on candidates ----
    if (lane < 32) {
        const int row = wrow0 + lane;                  // block-local 0..127
        const u32 K1 = sTop[wid][lane][0];
        const u32 K2 = sTop[wid][lane][1];
        const u32 K3 = sTop[wid][lane][2];
        int idx = (int)(K1 & 1023u);
        const u32 m1q = K1 >> 10, m2q = K2 >> 10;
        if (m2q - m1q <= 48u) {                        // widened hot threshold (csb-fold)
            const float* xr = x + (rowbase + (size_t)row) * DIM;
            float4 xv[16];
            #pragma unroll
            for (int q = 0; q < 16; ++q) xv[q] = reinterpret_cast<const float4*>(xr)[q];
            float p[4];
            #pragma unroll
            for (int q = 0; q < 4; ++q) {              // exact quarter chains
                float a = 0.f;
                #pragma unroll
                for (int e = 0; e < 4; ++e) {
                    const float4 v = xv[4 * q + e];
                    a = fmaf(v.x, v.x, a); a = fmaf(v.y, v.y, a);
                    a = fmaf(v.z, v.z, a); a = fmaf(v.w, v.w, a);
                }
                p[q] = a;
            }
            const float asq = (p[0] + p[1]) + (p[2] + p[3]);
            const u32 Mq = (u32)fmaf(asq, 0.126f, 24.0f);  // widened margin (csb-fold)
            u64 best = ~0ull;
            #pragma unroll 1
            for (int c = 0; c < 3; ++c) {
                const u32 Kc = c == 0 ? K1 : (c == 1 ? K2 : K3);
                const u32 mq = Kc >> 10;
                if (c > 0 && (mq - m1q) > Mq) break;   // keys sorted: later ones farther
                const int n = (int)(Kc & 1023u);
                const float4* cr = reinterpret_cast<const float4*>(cb + (size_t)n * DIM);
                float acc = 0.f;
                #pragma unroll
                for (int q = 0; q < 16; ++q) {         // exact sequential k-chain 0..63
                    const float4 c4 = cr[q], v = xv[q];
                    acc = fmaf(v.x, c4.x, acc); acc = fmaf(v.y, c4.y, acc);
                    acc = fmaf(v.z, c4.z, acc); acc = fmaf(v.w, c4.w, acc);
                }
                const float tt = asq - 2.0f * acc;     // ref rounding 1
                const float dd = tt + csq[n];          // ref rounding 2
                const u64 kk = ((u64)__float_as_uint(dd) << 32) | (u32)n;
                best = kk < best ? kk : best;
            }
            idx = (int)(u32)best;
        }
        sFinal[row] = idx;
        out_idx[rowbase + row] = (float)idx;
    }
    __syncthreads();

    // ---- epilogue: STE + loss in the identical 64-row units (2 per block) ----
    #pragma unroll 1
    for (int sub = 0; sub < 2; ++sub) {
        const size_t base = (rowbase + 64 * sub) * DIM;
        float lsum = 0.f;
        #pragma unroll 4
        for (int i = tid; i < 64 * DIM; i += 256) {
            const int r = i >> 6;
            const int d = i & 63;
            const int kb = sFinal[64 * sub + r];
            const float q  = cb[(size_t)kb * DIM + d];
            const float xe = x[base + i];
            out_q[base + i] = xe + (q - xe);            // STE forward, ref's rounding
            const float df = q - xe;
            lsum = fmaf(df, df, lsum);
        }
        #pragma unroll
        for (int off = 32; off; off >>= 1) lsum += __shfl_down(lsum, off, 64);
        if (lane == 0) sLoss[wid] = lsum;
        __syncthreads();
        if (tid == 0) {
            const float tot = (sLoss[0] + sLoss[1]) + (sLoss[2] + sLoss[3]);
            atomicAdd(out_loss, tot * (1.25f / 8388608.0f));
        }
        __syncthreads();
    }
}

extern "C" void kernel_launch(void* const* d_in, const int* in_sizes, int n_in,
                              void* d_out, int out_size, void* d_ws, size_t ws_size,
                              hipStream_t stream) {
    const float* x  = (const float*)d_in[0];   // 8388608
    const float* cb = (const float*)d_in[1];   // 65536
    float* out      = (float*)d_out;
    float* out_loss = out + QSIZE;             // [8388608]
    float* out_idx  = out + QSIZE + 1;         // [8388609 .. 8519680]

    float*   csq   = (float*)d_ws;             // 1024 f32
    float*   cs18b = csq + 1024;               // 1024 f32
    ushortx* cbsw  = (ushortx*)(csq + 2048);   // 65 tiles x 2048 ushorts (260 KB,
                                               // tile 64 = prefetch pad, uninit)

    vq_prep<<<16, 256, 0, stream>>>(cb, csq, cs18b, cbsw, out_loss);
    vq_main<<<NROWS / 128, 256, 0, stream>>>(x, cb, csq, cs18b, cbsw,
                                             out, out_loss, out_idx);
}

// Round 11
// 155.876 us; speedup vs baseline: 1.0370x; 1.0370x over previous
//
#include <hip/hip_runtime.h>

// VectorQuantizer forward: inputs [64,2048,64] f32, codebook [1024,64] f32.
// Outputs (f32, concat): quantized_ste [8388608], loss [1], indices-as-float [131072].
//
// Round 19: recombination of the two proven-best components.
//  - vq_main = R17 verbatim (88us, absmax 0): fragment-contiguous swizzled
//    codebook (TA fast path, the 163->88 win), fmaf key path, margins 26/+5.
//    R18's csb-fold + register prefetch REGRESSED main 88->97 (VGPR stayed 52:
//    compiler re-sank the loads and added copies; C-init movs cost more than
//    the saved fmaf) -> dropped.
//  - vq_prep = R18's 16-block parallel version (4 threads/code, exact quarter
//    chains shfl-combined in (p0+p1)+(p2+p3) order) WITHOUT the -2^19
//    pre-scale, so cbsw bits are identical to R17's.
//
// Numerics (= R17, absmax 0 verified): bf16 hi/lo split, 3-term
// mfma_f32_16x16x32_bf16 (|dot err| <= ~2e-6); argmin filter on m=cs-2dot
// quantized to u32 key ((m*2^18+bias)<<10|idx), top-3 per row via min/max
// network; rows with gap12 <= 26 quanta recheck EXACT d2 (sequential fmaf
// k=0..63, fl(fl(asq-2acc)+cs), u64 first-index-wins) for <=3 candidates
// within Mq = 0.126*asq+5. C/D layout: col=lane&15, row=(lane>>4)*4+reg
// (HW-verified). Loss/STE epilogue in identical 64-row units (2048
// identical partials, atomicAdd-accumulated).

#define NROWS  131072
#define DIM    64
#define KCB    1024
#define QSIZE  (NROWS * DIM)  // 8388608

typedef unsigned long long u64;
typedef unsigned int u32;
typedef unsigned short ushortx;
typedef __attribute__((ext_vector_type(8))) short short8v;
typedef __attribute__((ext_vector_type(4))) float f32x4;

__device__ __forceinline__ u32 umin32(u32 a, u32 b) { return a < b ? a : b; }
__device__ __forceinline__ u32 umax32(u32 a, u32 b) { return a > b ? a : b; }

// RNE f32 -> bf16 (deterministic, internal-only precision split)
__device__ __forceinline__ ushortx f2bf(float f) {
    u32 u = __float_as_uint(f);
    u32 r = u + 0x7FFFu + ((u >> 16) & 1u);
    return (ushortx)(r >> 16);
}
__device__ __forceinline__ float bf2f(ushortx h) {
    return __uint_as_float(((u32)h) << 16);
}

// ---- prep (parallel, 16 blocks x 256): csq exact quarter chains (4
// ---- threads/code, shfl-combined), cs18b, and the swizzled codebook.
// Layout (ushort units): tile ct stride 2048; sections of 512:
//   [ct*2048 + h*512        + L*8] = cbh[16ct+(L&15)][h*32+(L>>4)*8 .. +8]
//   [ct*2048 + 1024 + h*512 + L*8] = cbl[same]
__global__ __launch_bounds__(256) void vq_prep(const float* __restrict__ cb,
                                               float* __restrict__ csq,
                                               float* __restrict__ cs18b,
                                               ushortx* __restrict__ cbsw,
                                               float* __restrict__ loss_slot) {
    const int gid = blockIdx.x * 256 + threadIdx.x;   // 0..4095
    const int k  = gid >> 2;        // code 0..1023
    const int qt = gid & 3;         // dim quarter 16qt..16qt+15
    const float* c = cb + k * DIM;

    // exact 16-dim quarter chain
    float aq = 0.f;
    #pragma unroll
    for (int d = 0; d < 16; ++d) {
        const float v = c[16 * qt + d];
        aq = fmaf(v, v, aq);
    }
    // combine within 4-lane group: (p0+p1)+(p2+p3) exact order
    const float s1 = aq + __shfl_xor(aq, 1, 64);
    const float s2 = s1 + __shfl_xor(s1, 2, 64);
    if (qt == 0) {
        csq[k]   = s2;
        cs18b[k] = s2 * 262144.0f + 131072.0f;   // cs*2^18 + 2^17 bias
    }

    // swizzled writes: quarter qt covers 8-dim chunks 2qt, 2qt+1
    const int ct = k >> 4;
    const int j  = k & 15;
    #pragma unroll
    for (int cc = 0; cc < 2; ++cc) {
        const int c8 = 2 * qt + cc;     // global 8-dim chunk 0..7
        const int h  = c8 >> 2;         // dim half
        const int qq = c8 & 3;          // k-chunk within half
        const int L  = qq * 16 + j;     // destination lane
        union { ushortx u[8]; short8v v; } uh, ul;
        #pragma unroll
        for (int e = 0; e < 8; ++e) {
            const float f = c[c8 * 8 + e];
            const ushortx hh = f2bf(f);
            uh.u[e] = hh;
            ul.u[e] = f2bf(f - bf2f(hh));
        }
        *reinterpret_cast<short8v*>(cbsw + ct * 2048 + h * 512 + L * 8) = uh.v;
        *reinterpret_cast<short8v*>(cbsw + ct * 2048 + 1024 + h * 512 + L * 8) = ul.v;
    }
    if (gid == 0) *loss_slot = 0.f;
}

// ---- main: 256 threads = 4 waves; block = 128 rows (wave owns 32 rows =
// ---- 2 MFMA rowtiles -> 2 independent acc chains; sweeps all 1024 codes) ----
__global__ __launch_bounds__(256, 4) void vq_main(const float* __restrict__ x,
                                                  const float* __restrict__ cb,
                                                  const float* __restrict__ csq,
                                                  const float* __restrict__ cs18b,
                                                  const ushortx* __restrict__ cbsw,
                                                  float* __restrict__ out_q,
                                                  float* __restrict__ out_loss,
                                                  float* __restrict__ out_idx) {
    __shared__ u32   sTop[4][32][3];
    __shared__ int   sFinal[128];
    __shared__ float sLoss[4];

    const int tid  = threadIdx.x;
    const int lane = tid & 63;
    const int wid  = tid >> 6;            // 0..3
    const size_t rowbase = (size_t)blockIdx.x * 128;
    const int wrow0 = wid * 32;           // block-local first row of this wave
    const int lcol  = lane & 15;          // A-row-in-tile / B-col / D-col
    const int lkq   = lane >> 4;          // k-chunk 0..3

    // ---- A fragments: 2 rowtiles x 2 k-halves, hi/lo bf16 splits ----
    short8v Ah[2][2], Al[2][2];
    #pragma unroll
    for (int t = 0; t < 2; ++t)
        #pragma unroll
        for (int h = 0; h < 2; ++h) {
            const float* xp = x + (rowbase + (size_t)(wrow0 + t * 16 + lcol)) * DIM
                              + h * 32 + lkq * 8;
            const float4 u0 = *reinterpret_cast<const float4*>(xp);
            const float4 u1 = *reinterpret_cast<const float4*>(xp + 4);
            const float xv[8] = {u0.x, u0.y, u0.z, u0.w, u1.x, u1.y, u1.z, u1.w};
            union { ushortx u[8]; short8v v; } uh, ul;
            #pragma unroll
            for (int j = 0; j < 8; ++j) {
                const ushortx hh = f2bf(xv[j]);
                uh.u[j] = hh;
                ul.u[j] = f2bf(xv[j] - bf2f(hh));
            }
            Ah[t][h] = uh.v;
            Al[t][h] = ul.v;
        }

    // ---- code sweep: top-3 u32 keys per row-slot (8 slots/lane) ----
    u32 k1[8], k2[8], k3[8];
    #pragma unroll
    for (int s = 0; s < 8; ++s) { k1[s] = ~0u; k2[s] = ~0u; k3[s] = ~0u; }

    u32 nlane = (u32)lcol;
    const ushortx* bp = cbsw + (size_t)lane * 8;   // ideal coalesced: lane*16B

    #pragma unroll 1
    for (int ct = 0; ct < 64; ++ct) {     // 16 codes per tile
        const short8v Bh0 = *reinterpret_cast<const short8v*>(bp);
        const short8v Bh1 = *reinterpret_cast<const short8v*>(bp + 512);
        const short8v Bl0 = *reinterpret_cast<const short8v*>(bp + 1024);
        const short8v Bl1 = *reinterpret_cast<const short8v*>(bp + 1536);
        const float csb = cs18b[nlane];
        #pragma unroll
        for (int t = 0; t < 2; ++t) {     // 2 independent acc chains (ILP)
            f32x4 acc = (f32x4){0.f, 0.f, 0.f, 0.f};
            acc = __builtin_amdgcn_mfma_f32_16x16x32_bf16(Ah[t][0], Bh0, acc, 0, 0, 0);
            acc = __builtin_amdgcn_mfma_f32_16x16x32_bf16(Al[t][0], Bh0, acc, 0, 0, 0);
            acc = __builtin_amdgcn_mfma_f32_16x16x32_bf16(Ah[t][0], Bl0, acc, 0, 0, 0);
            acc = __builtin_amdgcn_mfma_f32_16x16x32_bf16(Ah[t][1], Bh1, acc, 0, 0, 0);
            acc = __builtin_amdgcn_mfma_f32_16x16x32_bf16(Al[t][1], Bh1, acc, 0, 0, 0);
            acc = __builtin_amdgcn_mfma_f32_16x16x32_bf16(Ah[t][1], Bl1, acc, 0, 0, 0);
            #pragma unroll
            for (int r = 0; r < 4; ++r) {
                const float m18 = fmaf(acc[r], -524288.0f, csb);  // (cs-2dot)*2^18+bias
                const u32 key = ((u32)m18 << 10) | nlane;          // trunc-cvt, monotone
                const int s = t * 4 + r;
                const u32 nk1 = umin32(key, k1[s]);
                const u32 mx  = umax32(key, k1[s]);
                const u32 nk2 = umin32(k2[s], mx);
                const u32 mx2 = umax32(k2[s], mx);
                k3[s] = umin32(k3[s], mx2);
                k1[s] = nk1; k2[s] = nk2;
            }
        }
        bp += 2048; nlane += 16;
    }

    // ---- merge the 16 col-classes per row (butterfly over lanes 16g..16g+15) ----
    #pragma unroll
    for (int s = 0; s < 8; ++s) {
        u32 a1 = k1[s], a2 = k2[s], a3 = k3[s];
        #pragma unroll
        for (int mask = 1; mask <= 8; mask <<= 1) {
            const u32 b1 = __shfl_xor(a1, mask, 64);
            const u32 b2 = __shfl_xor(a2, mask, 64);
            const u32 b3 = __shfl_xor(a3, mask, 64);
            const u32 c1 = umin32(a1, b1), d1 = umax32(a1, b1);
            const u32 c2 = umin32(a2, b2);
            const u32 o3 = umin32(umax32(d1, c2), umin32(a3, b3));
            a1 = c1; a2 = umin32(d1, c2); a3 = o3;
        }
        k1[s] = a1; k2[s] = a2; k3[s] = a3;
    }
    if (lcol < 8) {   // lane 16g+j writes slot j -> row (j>>2)*16 + g*4 + (j&3)
        const int j = lcol, g = lkq;
        const int row = (j >> 2) * 16 + g * 4 + (j & 3);
        sTop[wid][row][0] = k1[j]; sTop[wid][row][1] = k2[j]; sTop[wid][row][2] = k3[j];
    }
    __syncthreads();

    // ---- per-row final: non-hot -> min1; hot -> exact d2 (R12 chain) on candidates ----
    if (lane < 32) {
        const int row = wrow0 + lane;                  // block-local 0..127
        const u32 K1 = sTop[wid][lane][0];
        const u32 K2 = sTop[wid][lane][1];
        const u32 K3 = sTop[wid][lane][2];
        int idx = (int)(K1 & 1023u);
        const u32 m1q = K1 >> 10, m2q = K2 >> 10;
        if (m2q - m1q <= 26u) {                        // coarse hot (covers asq<=166)
            const float* xr = x + (rowbase + (size_t)row) * DIM;
            float4 xv[16];
            #pragma unroll
            for (int q = 0; q < 16; ++q) xv[q] = reinterpret_cast<const float4*>(xr)[q];
            float p[4];
            #pragma unroll
            for (int q = 0; q < 4; ++q) {              // exact quarter chains
                float a = 0.f;
                #pragma unroll
                for (int e = 0; e < 4; ++e) {
                    const float4 v = xv[4 * q + e];
                    a = fmaf(v.x, v.x, a); a = fmaf(v.y, v.y, a);
                    a = fmaf(v.z, v.z, a); a = fmaf(v.w, v.w, a);
                }
                p[q] = a;
            }
            const float asq = (p[0] + p[1]) + (p[2] + p[3]);
            const u32 Mq = (u32)fmaf(asq, 0.126f, 5.0f);   // safe ulp-derived margin
            u64 best = ~0ull;
            #pragma unroll 1
            for (int c = 0; c < 3; ++c) {
                const u32 Kc = c == 0 ? K1 : (c == 1 ? K2 : K3);
                const u32 mq = Kc >> 10;
                if (c > 0 && (mq - m1q) > Mq) break;   // keys sorted: later ones farther
                const int n = (int)(Kc & 1023u);
                const float4* cr = reinterpret_cast<const float4*>(cb + (size_t)n * DIM);
                float acc = 0.f;
                #pragma unroll
                for (int q = 0; q < 16; ++q) {         // exact sequential k-chain 0..63
                    const float4 c4 = cr[q], v = xv[q];
                    acc = fmaf(v.x, c4.x, acc); acc = fmaf(v.y, c4.y, acc);
                    acc = fmaf(v.z, c4.z, acc); acc = fmaf(v.w, c4.w, acc);
                }
                const float tt = asq - 2.0f * acc;     // ref rounding 1
                const float dd = tt + csq[n];          // ref rounding 2
                const u64 kk = ((u64)__float_as_uint(dd) << 32) | (u32)n;
                best = kk < best ? kk : best;
            }
            idx = (int)(u32)best;
        }
        sFinal[row] = idx;
        out_idx[rowbase + row] = (float)idx;
    }
    __syncthreads();

    // ---- epilogue: STE + loss in the identical 64-row units (2 per block) ----
    #pragma unroll 1
    for (int sub = 0; sub < 2; ++sub) {
        const size_t base = (rowbase + 64 * sub) * DIM;
        float lsum = 0.f;
        #pragma unroll 4
        for (int i = tid; i < 64 * DIM; i += 256) {
            const int r = i >> 6;
            const int d = i & 63;
            const int kb = sFinal[64 * sub + r];
            const float q  = cb[(size_t)kb * DIM + d];
            const float xe = x[base + i];
            out_q[base + i] = xe + (q - xe);            // STE forward, ref's rounding
            const float df = q - xe;
            lsum = fmaf(df, df, lsum);
        }
        #pragma unroll
        for (int off = 32; off; off >>= 1) lsum += __shfl_down(lsum, off, 64);
        if (lane == 0) sLoss[wid] = lsum;
        __syncthreads();
        if (tid == 0) {
            const float tot = (sLoss[0] + sLoss[1]) + (sLoss[2] + sLoss[3]);
            atomicAdd(out_loss, tot * (1.25f / 8388608.0f));
        }
        __syncthreads();
    }
}

extern "C" void kernel_launch(void* const* d_in, const int* in_sizes, int n_in,
                              void* d_out, int out_size, void* d_ws, size_t ws_size,
                              hipStream_t stream) {
    const float* x  = (const float*)d_in[0];   // 8388608
    const float* cb = (const float*)d_in[1];   // 65536
    float* out      = (float*)d_out;
    float* out_loss = out + QSIZE;             // [8388608]
    float* out_idx  = out + QSIZE + 1;         // [8388609 .. 8519680]

    float*   csq   = (float*)d_ws;             // 1024 f32
    float*   cs18b = csq + 1024;               // 1024 f32
    ushortx* cbsw  = (ushortx*)(csq + 2048);   // 64 tiles x 2048 ushorts (256 KB)

    vq_prep<<<16, 256, 0, stream>>>(cb, csq, cs18b, cbsw, out_loss);
    vq_main<<<NROWS / 128, 256, 0, stream>>>(x, cb, csq, cs18b, cbsw,
                                             out, out_loss, out_idx);
}